// Round 1
// baseline (4653.138 us; speedup 1.0000x reference)
//
#include <hip/hip_runtime.h>

// ---------------- constants ----------------
constexpr int NT = 64;     // timesteps
constexpr int NB = 64;     // batch
constexpr int NV = 32000;  // vocab
constexpr int NE = 512;    // embed
constexpr int NH = 512;    // hidden

constexpr size_t SZ_WRZ = 2ull * 1024 * 1024;       // [L][1024][1024]
constexpr size_t SZ_WH  = 2ull * 512 * 1024;        // [L][512][1024]
constexpr size_t SZ_OW  = (size_t)NV * NE;          // 16,384,000
constexpr size_t SZ_XE  = (size_t)NT * NB * NE;     // 2,097,152
constexpr size_t SZ_H   = (size_t)NB * NH;          // 32,768
constexpr size_t LOGITS = (size_t)NT * NB * NV;     // 131,072,000

typedef float f32x4 __attribute__((ext_vector_type(4)));
typedef short bf16x8 __attribute__((ext_vector_type(8)));
typedef _Float16 f16x8 __attribute__((ext_vector_type(8)));

// ---------------- helpers ----------------
__device__ __forceinline__ unsigned short f2bf(float x) {
  unsigned u = __float_as_uint(x);
  u += 0x7FFFu + ((u >> 16) & 1u);            // RNE
  return (unsigned short)(u >> 16);
}
__device__ __forceinline__ float bf2f(unsigned short s) {
  return __uint_as_float(((unsigned)s) << 16);
}
__device__ __forceinline__ void split2(float v, short* hi, short* lo) {
  unsigned short h = f2bf(v);
  *hi = (short)h;
  *lo = (short)f2bf(v - bf2f(h));
}
__device__ __forceinline__ f32x4 mma_bf16(bf16x8 a, bf16x8 b, f32x4 c) {
  return __builtin_amdgcn_mfma_f32_16x16x32_bf16(a, b, c, 0, 0, 0);
}
__device__ __forceinline__ f32x4 mma_f16(f16x8 a, f16x8 b, f32x4 c) {
  return __builtin_amdgcn_mfma_f32_16x16x32_f16(a, b, c, 0, 0, 0);
}

// device-scope barrier among all resident workgroups (monotonic counter)
__device__ __forceinline__ void gbar(unsigned* bar, unsigned target) {
  __threadfence();           // make this thread's writes device-visible
  __syncthreads();           // whole wg done + fenced
  if (threadIdx.x == 0)
    __hip_atomic_fetch_add(bar, 1u, __ATOMIC_RELEASE, __HIP_MEMORY_SCOPE_AGENT);
  while (__hip_atomic_load(bar, __ATOMIC_ACQUIRE, __HIP_MEMORY_SCOPE_AGENT) < target)
    __builtin_amdgcn_s_sleep(2);
  __syncthreads();
}

// ---------------- prep: split weights, embed, init state ----------------
__global__ void k_prep(
    const float* __restrict__ Wr, const float* __restrict__ Wz, const float* __restrict__ Wh,
    const float* __restrict__ outw, const int* __restrict__ toks,
    const float* __restrict__ emb, const float* __restrict__ hid,
    short* WrzHi, short* WrzLo, short* WhHi, short* WhLo, _Float16* OWf,
    short* XeHi, short* XeLo, short* X1Hi, short* X1Lo, short* h0Hi, short* h0Lo) {
  const size_t stride = (size_t)gridDim.x * blockDim.x;
  const size_t N1 = SZ_WRZ, N2 = N1 + SZ_WH, N3 = N2 + SZ_OW,
               N4 = N3 + SZ_XE, N5 = N4 + SZ_H, N6 = N5 + SZ_H;
  for (size_t x = (size_t)blockIdx.x * blockDim.x + threadIdx.x; x < N6; x += stride) {
    if (x < N1) {
      size_t l = x >> 20, rem = x & 1048575u;
      size_t row = rem >> 10, k = rem & 1023u;
      float v = (row < 512) ? Wr[(l * 512 + row) * 1024 + k]
                            : Wz[(l * 512 + (row - 512)) * 1024 + k];
      short hi, lo; split2(v, &hi, &lo);
      WrzHi[x] = hi; WrzLo[x] = lo;
    } else if (x < N2) {
      size_t p = x - N1;
      short hi, lo; split2(Wh[p], &hi, &lo);
      WhHi[p] = hi; WhLo[p] = lo;
    } else if (x < N3) {
      size_t p = x - N2;
      OWf[p] = (_Float16)outw[p];
    } else if (x < N4) {
      size_t p = x - N3;
      size_t r = p >> 9, c = p & 511u;
      int tok = toks[r];
      float v = emb[(size_t)tok * 512 + c];
      short hi, lo; split2(v, &hi, &lo);
      XeHi[p] = hi; XeLo[p] = lo;
    } else if (x < N5) {
      size_t p = x - N4;
      short hi, lo; split2(hid[p], &hi, &lo);
      h0Hi[p] = hi; h0Lo[p] = lo;
    } else {
      size_t p = x - N5;
      short hi, lo; split2(hid[SZ_H + p], &hi, &lo);
      X1Hi[p] = hi; X1Lo[p] = lo;
    }
  }
}

// ---------------- recurrence phases ----------------
// Phase A: pre = [aLo | aHi] @ Wrz[jc..jc+32).T ; sigmoid; r-cols -> rh (split), z-cols -> z
__device__ __forceinline__ void phaseA(
    const short* __restrict__ aLoH, const short* __restrict__ aLoL,
    const short* __restrict__ aHiH, const short* __restrict__ aHiL,
    const short* __restrict__ wHi, const short* __restrict__ wLo,
    const float* __restrict__ br, const float* __restrict__ bz,
    const short* __restrict__ hH, const short* __restrict__ hL,
    short* rhHi, short* rhLo, float* zOut,
    int jc, int wave, int l15, int lq) {
  f32x4 acc0 = {0.f, 0.f, 0.f, 0.f}, acc1 = {0.f, 0.f, 0.f, 0.f};
  const int rowA = wave * 16 + l15;
  const int j0 = jc + l15, j1 = j0 + 16;
  for (int k0 = 0; k0 < 1024; k0 += 32) {
    const int kk = k0 + lq * 8;
    const short *pH, *pL;
    if (kk < 512) { pH = aLoH + rowA * 512 + kk;        pL = aLoL + rowA * 512 + kk; }
    else          { pH = aHiH + rowA * 512 + (kk - 512); pL = aHiL + rowA * 512 + (kk - 512); }
    bf16x8 ah = *(const bf16x8*)pH;
    bf16x8 al = *(const bf16x8*)pL;
    bf16x8 b0h = *(const bf16x8*)(wHi + (size_t)j0 * 1024 + kk);
    bf16x8 b0l = *(const bf16x8*)(wLo + (size_t)j0 * 1024 + kk);
    bf16x8 b1h = *(const bf16x8*)(wHi + (size_t)j1 * 1024 + kk);
    bf16x8 b1l = *(const bf16x8*)(wLo + (size_t)j1 * 1024 + kk);
    acc0 = mma_bf16(ah, b0h, acc0);
    acc1 = mma_bf16(ah, b1h, acc1);
    acc0 = mma_bf16(al, b0h, acc0);
    acc1 = mma_bf16(al, b1h, acc1);
    acc0 = mma_bf16(ah, b0l, acc0);
    acc1 = mma_bf16(ah, b1l, acc1);
  }
#pragma unroll
  for (int tile = 0; tile < 2; ++tile) {
    f32x4 acc = tile ? acc1 : acc0;
    const int j = jc + tile * 16 + l15;
#pragma unroll
    for (int r = 0; r < 4; ++r) {
      const int b = wave * 16 + lq * 4 + r;
      float pre = acc[r] + ((j < 512) ? br[j] : bz[j - 512]);
      float s = 1.0f / (1.0f + __expf(-pre));
      if (j < 512) {
        float hv = bf2f((unsigned short)hH[b * 512 + j]) + bf2f((unsigned short)hL[b * 512 + j]);
        float rh = s * hv;
        short hi, lo; split2(rh, &hi, &lo);
        rhHi[b * 512 + j] = hi; rhLo[b * 512 + j] = lo;
      } else {
        zOut[b * 512 + (j - 512)] = s;
      }
    }
  }
}

// Phase B: hh = tanh([aLo | aHi] @ Wh[jc..jc+16).T + bh); hNew = (1-z)*hOld + z*hh
__device__ __forceinline__ void phaseB(
    const short* __restrict__ aLoH, const short* __restrict__ aLoL,
    const short* __restrict__ aHiH, const short* __restrict__ aHiL,
    const short* __restrict__ wHi, const short* __restrict__ wLo,
    const float* __restrict__ bh, const float* __restrict__ zIn,
    const short* __restrict__ hOldH, const short* __restrict__ hOldL,
    short* hNewH, short* hNewL, _Float16* xf16, float* hidOut,
    int jc, int wave, int l15, int lq) {
  f32x4 acc = {0.f, 0.f, 0.f, 0.f};
  const int rowA = wave * 16 + l15;
  const int j = jc + l15;
  for (int k0 = 0; k0 < 1024; k0 += 32) {
    const int kk = k0 + lq * 8;
    const short *pH, *pL;
    if (kk < 512) { pH = aLoH + rowA * 512 + kk;        pL = aLoL + rowA * 512 + kk; }
    else          { pH = aHiH + rowA * 512 + (kk - 512); pL = aHiL + rowA * 512 + (kk - 512); }
    bf16x8 ah = *(const bf16x8*)pH;
    bf16x8 al = *(const bf16x8*)pL;
    bf16x8 bhh = *(const bf16x8*)(wHi + (size_t)j * 1024 + kk);
    bf16x8 bhl = *(const bf16x8*)(wLo + (size_t)j * 1024 + kk);
    acc = mma_bf16(ah, bhh, acc);
    acc = mma_bf16(al, bhh, acc);
    acc = mma_bf16(ah, bhl, acc);
  }
#pragma unroll
  for (int r = 0; r < 4; ++r) {
    const int b = wave * 16 + lq * 4 + r;
    float pre = acc[r] + bh[j];
    float hh = tanhf(pre);
    float z = zIn[b * 512 + j];
    float ho = bf2f((unsigned short)hOldH[b * 512 + j]) + bf2f((unsigned short)hOldL[b * 512 + j]);
    float hn = (1.0f - z) * ho + z * hh;
    short hi, lo; split2(hn, &hi, &lo);
    hNewH[b * 512 + j] = hi; hNewL[b * 512 + j] = lo;
    if (xf16)   xf16[b * 512 + j] = (_Float16)hn;
    if (hidOut) hidOut[b * 512 + j] = hn;
  }
}

// Persistent recurrence kernel: 64 wgs, 2 barrier-rounds per timestep
// (layer0 t=m pipelined against layer1 t=m-1).
__launch_bounds__(256, 1)
__global__ void k_recur(
    const short* __restrict__ XeHi, const short* __restrict__ XeLo,
    const short* __restrict__ WrzHi, const short* __restrict__ WrzLo,
    const short* __restrict__ WhHi, const short* __restrict__ WhLo,
    const float* __restrict__ Wrb, const float* __restrict__ Wzb, const float* __restrict__ Whb,
    short* X1Hi, short* X1Lo, _Float16* X1f16,
    short* h0Hi, short* h0Lo,
    short* rh0Hi, short* rh0Lo, short* rh1Hi, short* rh1Lo,
    float* z0, float* z1, float* hidOut, unsigned* bar) {
  const int wg = blockIdx.x;          // 0..63
  const int tid = threadIdx.x;
  const int wave = tid >> 6, lane = tid & 63;
  const int l15 = lane & 15, lq = lane >> 4;
  unsigned round = 0;

  for (int m = 0; m <= NT; ++m) {
    // -------- phase A: r,z gates (layer0 t=m || layer1 t=m-1) --------
    if (wg < 32) {
      if (m < NT) {
        const int t = m;
        phaseA(XeHi + (size_t)t * NB * NE, XeLo + (size_t)t * NB * NE,
               h0Hi + (size_t)(m & 1) * SZ_H, h0Lo + (size_t)(m & 1) * SZ_H,
               WrzHi, WrzLo, Wrb, Wzb,
               h0Hi + (size_t)(m & 1) * SZ_H, h0Lo + (size_t)(m & 1) * SZ_H,
               rh0Hi, rh0Lo, z0, wg * 32, wave, l15, lq);
      }
    } else {
      if (m >= 1) {
        const int t = m - 1;
        phaseA(h0Hi + (size_t)(m & 1) * SZ_H, h0Lo + (size_t)(m & 1) * SZ_H,   // x1 = h0 after t
               X1Hi + (size_t)t * SZ_H, X1Lo + (size_t)t * SZ_H,               // h1 state
               WrzHi + (size_t)1024 * 1024, WrzLo + (size_t)1024 * 1024,
               Wrb + 512, Wzb + 512,
               X1Hi + (size_t)t * SZ_H, X1Lo + (size_t)t * SZ_H,
               rh1Hi, rh1Lo, z1, (wg - 32) * 32, wave, l15, lq);
      }
    }
    ++round; gbar(bar, round * 64u);

    // -------- phase B: candidate + state update --------
    if (wg < 32) {
      if (m < NT) {
        const int t = m;
        phaseB(XeHi + (size_t)t * NB * NE, XeLo + (size_t)t * NB * NE,
               rh0Hi, rh0Lo, WhHi, WhLo, Whb, z0,
               h0Hi + (size_t)(m & 1) * SZ_H, h0Lo + (size_t)(m & 1) * SZ_H,
               h0Hi + (size_t)((m + 1) & 1) * SZ_H, h0Lo + (size_t)((m + 1) & 1) * SZ_H,
               (_Float16*)nullptr,
               (m == NT - 1) ? hidOut : nullptr,
               wg * 16, wave, l15, lq);
      }
    } else {
      if (m >= 1) {
        const int t = m - 1;
        phaseB(h0Hi + (size_t)(m & 1) * SZ_H, h0Lo + (size_t)(m & 1) * SZ_H,
               rh1Hi, rh1Lo,
               WhHi + (size_t)512 * 1024, WhLo + (size_t)512 * 1024, Whb + 512, z1,
               X1Hi + (size_t)t * SZ_H, X1Lo + (size_t)t * SZ_H,
               X1Hi + (size_t)(t + 1) * SZ_H, X1Lo + (size_t)(t + 1) * SZ_H,
               X1f16 + (size_t)t * SZ_H,
               (m == NT) ? hidOut + SZ_H : nullptr,
               (wg - 32) * 16, wave, l15, lq);
      }
    }
    ++round; gbar(bar, round * 64u);
  }
}

// ---------------- final logits GEMM: C[4096,32000] = X1f16 @ OWf^T + bias ----------------
__launch_bounds__(256, 2)
__global__ void k_gemm(const _Float16* __restrict__ A, const _Float16* __restrict__ Bw,
                       const float* __restrict__ bias, float* __restrict__ C) {
  __shared__ _Float16 lsA[128 * 64];
  __shared__ _Float16 lsB[128 * 64];
  const int bm = blockIdx.x;   // 0..31  (M blocks)
  const int bn = blockIdx.y;   // 0..249 (N blocks)
  const int tid = threadIdx.x;
  const int wave = tid >> 6, lane = tid & 63;
  const int l15 = lane & 15, lq = lane >> 4;
  const int wr = (wave >> 1) * 64, wc = (wave & 1) * 64;
  f32x4 acc[4][4] = {};
  const size_t arow0 = (size_t)bm * 128;
  const size_t brow0 = (size_t)bn * 128;

  for (int kb = 0; kb < 512; kb += 64) {
    // stage A/B tiles (reg-staged, XOR-swizzled LDS layout)
#pragma unroll
    for (int i = 0; i < 4; ++i) {
      int c = tid + i * 256;                 // 0..1023 chunks of 8 f16
      int row = c >> 3, kc = (c & 7) * 8;
      f16x8 va = *(const f16x8*)(A  + (arow0 + row) * 512 + kb + kc);
      f16x8 vb = *(const f16x8*)(Bw + (brow0 + row) * 512 + kb + kc);
      int el = (row * 64 + kc) ^ ((row & 7) << 3);
      *(f16x8*)&lsA[el] = va;
      *(f16x8*)&lsB[el] = vb;
    }
    __syncthreads();
#pragma unroll
    for (int k0 = 0; k0 < 64; k0 += 32) {
      const int kk = k0 + lq * 8;
      f16x8 af[4], bf_[4];
#pragma unroll
      for (int i = 0; i < 4; ++i) {
        int ra = wr + i * 16 + l15;
        af[i]  = *(const f16x8*)&lsA[(ra * 64 + kk) ^ ((ra & 7) << 3)];
        int rb = wc + i * 16 + l15;
        bf_[i] = *(const f16x8*)&lsB[(rb * 64 + kk) ^ ((rb & 7) << 3)];
      }
#pragma unroll
      for (int i = 0; i < 4; ++i)
#pragma unroll
        for (int jt = 0; jt < 4; ++jt)
          acc[i][jt] = mma_f16(af[i], bf_[jt], acc[i][jt]);
    }
    __syncthreads();
  }
  // epilogue
#pragma unroll
  for (int i = 0; i < 4; ++i) {
#pragma unroll
    for (int jt = 0; jt < 4; ++jt) {
      const size_t col = brow0 + wc + jt * 16 + l15;
      const float bval = bias[col];
#pragma unroll
      for (int r = 0; r < 4; ++r) {
        const size_t row = arow0 + wr + i * 16 + lq * 4 + r;
        C[row * (size_t)NV + col] = acc[i][jt][r] + bval;
      }
    }
  }
}

// ---------------- launcher ----------------
extern "C" void kernel_launch(void* const* d_in, const int* in_sizes, int n_in,
                              void* d_out, int out_size, void* d_ws, size_t ws_size,
                              hipStream_t stream) {
  (void)in_sizes; (void)n_in; (void)out_size; (void)ws_size;
  const int*   toks = (const int*)d_in[0];
  const float* hid  = (const float*)d_in[1];
  const float* emb  = (const float*)d_in[2];
  const float* Wr   = (const float*)d_in[3];
  const float* Wrb  = (const float*)d_in[4];
  const float* Wz   = (const float*)d_in[5];
  const float* Wzb  = (const float*)d_in[6];
  const float* Wh   = (const float*)d_in[7];
  const float* Whb  = (const float*)d_in[8];
  const float* outw = (const float*)d_in[9];
  const float* outb = (const float*)d_in[10];
  float* out = (float*)d_out;

  char* base = (char*)d_ws;
  size_t off = 0;
  auto carve = [&](size_t bytes) -> char* {
    char* r = base + off;
    off = (off + bytes + 255) & ~(size_t)255;
    return r;
  };
  short*    WrzHi = (short*)carve(SZ_WRZ * 2);
  short*    WrzLo = (short*)carve(SZ_WRZ * 2);
  short*    WhHi  = (short*)carve(SZ_WH * 2);
  short*    WhLo  = (short*)carve(SZ_WH * 2);
  _Float16* OWf   = (_Float16*)carve(SZ_OW * 2);
  short*    XeHi  = (short*)carve(SZ_XE * 2);
  short*    XeLo  = (short*)carve(SZ_XE * 2);
  short*    X1Hi  = (short*)carve((size_t)(NT + 1) * SZ_H * 2);
  short*    X1Lo  = (short*)carve((size_t)(NT + 1) * SZ_H * 2);
  _Float16* X1f16 = (_Float16*)carve((size_t)NT * SZ_H * 2);
  short*    h0Hi  = (short*)carve(2 * SZ_H * 2);
  short*    h0Lo  = (short*)carve(2 * SZ_H * 2);
  short*    rh0Hi = (short*)carve(SZ_H * 2);
  short*    rh0Lo = (short*)carve(SZ_H * 2);
  short*    rh1Hi = (short*)carve(SZ_H * 2);
  short*    rh1Lo = (short*)carve(SZ_H * 2);
  float*    z0    = (float*)carve(SZ_H * 4);
  float*    z1    = (float*)carve(SZ_H * 4);
  unsigned* bar   = (unsigned*)carve(256);

  hipMemsetAsync(bar, 0, 256, stream);

  k_prep<<<4096, 256, 0, stream>>>(Wr, Wz, Wh, outw, toks, emb, hid,
                                   WrzHi, WrzLo, WhHi, WhLo, OWf,
                                   XeHi, XeLo, X1Hi, X1Lo, h0Hi, h0Lo);

  k_recur<<<64, 256, 0, stream>>>(XeHi, XeLo, WrzHi, WrzLo, WhHi, WhLo,
                                  Wrb, Wzb, Whb,
                                  X1Hi, X1Lo, X1f16, h0Hi, h0Lo,
                                  rh0Hi, rh0Lo, rh1Hi, rh1Lo, z0, z1,
                                  out + LOGITS, bar);

  dim3 g(32, 250);
  k_gemm<<<g, 256, 0, stream>>>(X1f16, OWf, outb, out);
}